// Round 4
// baseline (5332.335 us; speedup 1.0000x reference)
//
#include <hip/hip_runtime.h>

// GRUPlant tensor-parallel persistent kernel, round 9 = round-5 compute VERBATIM
// + side-channel XCD diagnostic (timing-leak only; output bytes identical).
// r6/r7/r8 all failed opaquely; this round re-anchors on the proven kernel and
// tests ONLY the two unproven ingredients: (a) s_getreg_b32 hwreg(HW_REG_XCC_ID)
// (symbolic, m09-proven form), (b) whether remapped groups {bid&15} are
// XCD-uniform under real dispatch. Verdict leaked via ~2ms delay in block 0.

typedef _Float16 f16x8 __attribute__((ext_vector_type(8)));
typedef float f32x4 __attribute__((ext_vector_type(4)));

#define XSTR 104   // 96 + 8 pad (f16)
#define HSTR 264   // 256 + 8 pad (f16)
#define YSTR 136   // 128 + 8 pad (f16)

// ---- pre-swizzled weight layout in d_ws (f16 elems; chunk = 512 f16 = 1KB) ----
#define OFF_E0IH 0u
#define OFF_E0HH 73728u
#define OFF_E1IH 270336u
#define OFF_E1HH 466944u
#define OFF_D0IH 663552u     // K=80 zero-padded to 96
#define OFF_D0HH 737280u
#define OFF_D1IH 933888u
#define OFF_D1HH 1130496u
#define OFF_FC1  1327104u    // 8kt x 8gt
#define OFF_FC2  1359872u    // 4kt x 1gt
#define W_TOTAL_F16 1361920u
#define BIAS_BYTE_OFF 2723840u
#define EXCH_BYTE_OFF 2740224u
// ---- exchange region (bytes, relative) ---- (EXACT round-5 footprint)
#define EX_H0 0          // [2][256][256] f16
#define EX_H1 262144     // [2][256][256] f16
#define EX_PV 524288     // [256][16] f16
#define EX_FLAGS 532480  // 16 groups x 17 flags x 128 B (int[0]=flag;
                         // int[16] at +64B = diagnostic handshake slot)
#define EX_BYTES 567296

__device__ __forceinline__ float sigm(float x) { return 1.f / (1.f + __expf(-x)); }
__device__ __forceinline__ float tanh_fast(float x) { return 1.f - 2.f / (__expf(2.f * x) + 1.f); }

__device__ __forceinline__ f32x4 mfma(f16x8 a, f16x8 b, f32x4 c) {
    return __builtin_amdgcn_mfma_f32_16x16x32_f16(a, b, c, 0, 0, 0);
}

// ---- coherent (IC-level) memory helpers: bypass L1+L2 via sc0 sc1 ----
__device__ __forceinline__ void store_coh_f16(_Float16* p, _Float16 v) {
    union { _Float16 h; unsigned short u; } cv; cv.h = v;
    unsigned int ui = cv.u;
    asm volatile("global_store_short %0, %1, off sc0 sc1" :: "v"(p), "v"(ui) : "memory");
}
__device__ __forceinline__ unsigned short load_coh_u16(const _Float16* p) {
    unsigned int r;
    asm volatile("global_load_ushort %0, %1, off sc0 sc1\n\ts_waitcnt vmcnt(0)"
                 : "=v"(r) : "v"(p) : "memory");
    return (unsigned short)r;
}

// cooperative: stage one 16x256 f16 h-matrix (rows stride 256) into LDS (stride HSTR)
__device__ __forceinline__ void stage_h(const _Float16* src, _Float16* dst, int tid) {
    if (tid < 256) {
        int row = tid >> 4, c = tid & 15;
        const _Float16* p = src + (size_t)row * 256 + c * 16;
        f16x8 a, b;
        asm volatile(
            "global_load_dwordx4 %0, %2, off sc0 sc1\n\t"
            "global_load_dwordx4 %1, %2, off offset:16 sc0 sc1\n\t"
            "s_waitcnt vmcnt(0)"
            : "=v"(a), "=v"(b) : "v"(p) : "memory");
        *(f16x8*)(dst + row * HSTR + c * 16) = a;
        *(f16x8*)(dst + row * HSTR + c * 16 + 8) = b;
    }
}
// two matrices, one waitcnt
__device__ __forceinline__ void stage_h2(const _Float16* s0, const _Float16* s1,
                                         _Float16* d0, _Float16* d1, int tid) {
    if (tid < 256) {
        int row = tid >> 4, c = tid & 15;
        const _Float16* p0 = s0 + (size_t)row * 256 + c * 16;
        const _Float16* p1 = s1 + (size_t)row * 256 + c * 16;
        f16x8 a, b, e, f;
        asm volatile(
            "global_load_dwordx4 %0, %4, off sc0 sc1\n\t"
            "global_load_dwordx4 %1, %4, off offset:16 sc0 sc1\n\t"
            "global_load_dwordx4 %2, %5, off sc0 sc1\n\t"
            "global_load_dwordx4 %3, %5, off offset:16 sc0 sc1\n\t"
            "s_waitcnt vmcnt(0)"
            : "=v"(a), "=v"(b), "=v"(e), "=v"(f) : "v"(p0), "v"(p1) : "memory");
        *(f16x8*)(d0 + row * HSTR + c * 16) = a;
        *(f16x8*)(d0 + row * HSTR + c * 16 + 8) = b;
        *(f16x8*)(d1 + row * HSTR + c * 16) = e;
        *(f16x8*)(d1 + row * HSTR + c * 16 + 8) = f;
    }
}

// ---- prep: swizzle (rows x K_src) fp32 weight into MFMA-B fragment chunks ----
__global__ __launch_bounds__(256) void prep_w(const float* __restrict__ W,
                                              _Float16* __restrict__ dst,
                                              int K_src, int GT, int total_threads) {
    int idx = blockIdx.x * 256 + threadIdx.x;
    if (idx >= total_threads) return;
    int l = idx & 63, c = idx >> 6;
    int kt = c / GT, gt = c - kt * GT;
    int g = gt * 16 + (l & 15);
    int k0 = kt * 32 + (l >> 4) * 8;
    _Float16 tmp[8];
#pragma unroll
    for (int j = 0; j < 8; ++j) {
        int k = k0 + j;
        tmp[j] = (k < K_src) ? (_Float16)W[(size_t)g * K_src + k] : (_Float16)0.f;
    }
    *(f16x8*)(dst + (size_t)c * 512 + (size_t)l * 8) = *(f16x8*)tmp;
}

__global__ __launch_bounds__(256) void prep_bias(const float* __restrict__ bih,
                                                 const float* __restrict__ bhh,
                                                 float* __restrict__ dst) {
    int i = threadIdx.x;
    dst[i]       = bih[i]       + bhh[i];
    dst[256 + i] = bih[256 + i] + bhh[256 + i];
    dst[512 + i] = bih[512 + i];
    dst[768 + i] = bhh[512 + i];
}

template <int KT>
__device__ __forceinline__ f32x4 mmk(const _Float16* ap, const f16x8 (&B)[8]) {
    f32x4 acc = {0.f, 0.f, 0.f, 0.f};
#pragma unroll
    for (int kt = 0; kt < KT; ++kt)
        acc = mfma(*(const f16x8*)(ap + kt * 32), B[kt], acc);
    return acc;
}

__device__ __forceinline__ void h_update(const float* Gb, float* HM,
                                         _Float16* hex_slice, int l,
                                         float bR, float bZ, float bNi, float bNh) {
#pragma unroll
    for (int i = 0; i < 4; ++i) {
        int row = (l >> 4) * 4 + i, col = l & 15;
        int rc = row * 17 + col;
        float r = sigm(Gb[rc] + bR);
        float z = sigm(Gb[272 + rc] + bZ);
        float n = tanh_fast(Gb[2 * 272 + rc] + bNi + r * (Gb[3 * 272 + rc] + bNh));
        float hp = HM[row * 16 + col];
        float hn = (1.f - z) * n + z * hp;
        HM[row * 16 + col] = hn;
        store_coh_f16(hex_slice + (size_t)row * 256 + col, (_Float16)hn);
    }
}

__global__ __launch_bounds__(384, 2) void plant(
    const float* __restrict__ x_cv, const float* __restrict__ x_tgt,
    const float* __restrict__ pv_init, const int* __restrict__ scen,
    const float* __restrict__ emb,
    const _Float16* __restrict__ Wsw, const float* __restrict__ bias4,
    const float* __restrict__ fc1b, const float* __restrict__ fc2b,
    char* __restrict__ exch, float* __restrict__ out)
{
    __shared__ _Float16 XF[16 * XSTR];
    __shared__ _Float16 HA0[16 * HSTR];
    __shared__ _Float16 HA1[16 * HSTR];
    __shared__ _Float16 YF[16 * YSTR];
    __shared__ float G[2][4][272];
    __shared__ float H0M[256], H1M[256];

    const int tid = threadIdx.x;
    const int l = tid & 63, w = tid >> 6;
    const int g = blockIdx.x >> 4, cg = blockIdx.x & 15;
    const int g16 = g * 16;
    const int j = (w < 3) ? w : w - 3;      // gate role: 0=r,1=z,2=n
    const int gt = j * 16 + cg;

    _Float16* h0ex = (_Float16*)(exch + EX_H0);
    _Float16* h1ex = (_Float16*)(exch + EX_H1);
    _Float16* pvex = (_Float16*)(exch + EX_PV);
    int* gflags = (int*)(exch + EX_FLAGS) + g * (17 * 32);
    int* pvflag = gflags + 16 * 32;

    // ---- DIAGNOSTIC (timing-leak only; touches ONLY spare +64B dwords of
    // flag lines 0..15, never int[0]; compute below is round-5 verbatim).
    // Tests whether the remapped grouping hg = bid&15 is XCD-uniform.
    if (tid == 0) {
        int xcd;
        asm volatile("s_getreg_b32 %0, hwreg(HW_REG_XCC_ID)" : "=s"(xcd));
        const int hg = blockIdx.x & 15, hcg = blockIdx.x >> 4;
        int* hbase = (int*)(exch + EX_FLAGS) + hg * (17 * 32) + 16;
        int tag = (xcd & 0xF) + 1;
        __hip_atomic_store(hbase + hcg * 32, tag, __ATOMIC_RELAXED,
                           __HIP_MEMORY_SCOPE_AGENT);
        int ok = 1;
        for (int m = 0; m < 16; ++m) {
            int v;
            do {
                v = __hip_atomic_load(hbase + m * 32, __ATOMIC_RELAXED,
                                      __HIP_MEMORY_SCOPE_AGENT);
                if (v == 0) __builtin_amdgcn_s_sleep(4);
            } while (v == 0);
            ok &= (v == tag);
        }
        if (ok && blockIdx.x == 0) {
            // ~2 ms dependent-FMA delay: dur >> 3500us signals verdict=1
            float x = (float)tag;
            for (int it = 0; it < 1000000; ++it)
                x = __builtin_fmaf(x, 0.9999f, 1e-7f);
            asm volatile("" :: "v"(x));
        }
    }

    const int arow = l & 15, acol8 = (l >> 4) * 8;
    const size_t slice_off = (size_t)g16 * 256 + cg * 16;
    const _Float16* XFp = XF + arow * XSTR + acol8;
    const _Float16* HA0p = HA0 + arow * HSTR + acol8;
    const _Float16* HA1p = HA1 + arow * HSTR + acol8;

    int ticket = 0;
    auto barrier = [&](int target) {
        __syncthreads();   // drains vmcnt(0) per wave -> all coherent stores done
        if (w == 0) {
            if (l == 0)
                __hip_atomic_store(&gflags[cg * 32], target, __ATOMIC_RELAXED,
                                   __HIP_MEMORY_SCOPE_AGENT);
            if (l < 16)
                while (__hip_atomic_load(&gflags[l * 32], __ATOMIC_RELAXED,
                                         __HIP_MEMORY_SCOPE_AGENT) < target)
                    __builtin_amdgcn_s_sleep(1);
        }
        __syncthreads();
    };

    // ---- init ----
    for (int i = tid; i < 256; i += 384) { H0M[i] = 0.f; H1M[i] = 0.f; }
    if (tid < 256) {                        // scenario embedding -> XF[64..95]
        int row = tid >> 4, c2 = (tid & 15) * 2;
        int sc = scen[g16 + row];
        XF[row * XSTR + 64 + c2]     = (_Float16)emb[sc * 32 + c2];
        XF[row * XSTR + 64 + c2 + 1] = (_Float16)emb[sc * 32 + c2 + 1];
    }

    // encoder gate weights -> registers
    f16x8 Bx[8], Bh[8];
    {
        unsigned offi = (w < 3) ? OFF_E0IH : OFF_E1IH;
        unsigned offh = (w < 3) ? OFF_E0HH : OFF_E1HH;
        int ktx = (w < 3) ? 3 : 8;
#pragma unroll
        for (int kt = 0; kt < 8; ++kt) {
            if (kt < ktx) Bx[kt] = *(const f16x8*)(Wsw + offi + (size_t)(kt * 48 + gt) * 512 + l * 8);
            Bh[kt] = *(const f16x8*)(Wsw + offh + (size_t)(kt * 48 + gt) * 512 + l * 8);
        }
    }
    float bR = 0.f, bZ = 0.f, bNi = 0.f, bNh = 0.f;
    {
        const float* bb = (w == 0) ? bias4 : bias4 + 1024;
        int hc = cg * 16 + (l & 15);
        if (w == 0 || w == 3) { bR = bb[hc]; bZ = bb[256 + hc]; bNi = bb[512 + hc]; bNh = bb[768 + hc]; }
    }

    float4 xpre;
    const float* xsrc0 = x_cv + (size_t)(g16 + (tid >> 4)) * (512 * 64) + (tid & 15) * 4;
    if (tid < 256) xpre = *(const float4*)xsrc0;
    __syncthreads();

    // ================= encoder: t = 0..512 (layer1 lags by 1) =================
    for (int t = 0; t <= 512; ++t) {
        if (t < 512 && tid < 256) {
            int row = tid >> 4, c4 = (tid & 15) * 4;
            XF[row * XSTR + c4]     = (_Float16)xpre.x;
            XF[row * XSTR + c4 + 1] = (_Float16)xpre.y;
            XF[row * XSTR + c4 + 2] = (_Float16)xpre.z;
            XF[row * XSTR + c4 + 3] = (_Float16)xpre.w;
        }
        stage_h2(h0ex + (size_t)((t - 1) & 1) * 65536 + (size_t)g16 * 256,
                 h1ex + (size_t)(t & 1) * 65536 + (size_t)g16 * 256, HA0, HA1, tid);
        __syncthreads();
        if (tid < 256 && t + 1 < 512) xpre = *(const float4*)(xsrc0 + (size_t)(t + 1) * 64);

        bool doL0 = (w < 3) && (t < 512);
        bool doL1 = (w >= 3) && (t > 0);
        if (doL0 || doL1) {
            f32x4 accX, accH;
            if (doL0) { accX = mmk<3>(XFp, Bx);  accH = mmk<8>(HA0p, Bh); }
            else      { accX = mmk<8>(HA0p, Bx); accH = mmk<8>(HA1p, Bh); }
            float* Gb = &G[(w < 3) ? 0 : 1][0][0];
#pragma unroll
            for (int i = 0; i < 4; ++i) {
                int rc = ((l >> 4) * 4 + i) * 17 + (l & 15);
                if (j < 2) Gb[j * 272 + rc] = accX[i] + accH[i];
                else { Gb[2 * 272 + rc] = accX[i]; Gb[3 * 272 + rc] = accH[i]; }
            }
        }
        __syncthreads();
        if (w == 0 && t < 512)
            h_update(&G[0][0][0], H0M, h0ex + (size_t)(t & 1) * 65536 + slice_off, l, bR, bZ, bNi, bNh);
        if (w == 3 && t > 0)
            h_update(&G[1][0][0], H1M, h1ex + (size_t)((t - 1) & 1) * 65536 + slice_off, l, bR, bZ, bNi, bNh);
        barrier(++ticket);
    }

    // ================= phase switch: decoder weights =================
    {
        unsigned offi = (w < 3) ? OFF_D0IH : OFF_D1IH;
        unsigned offh = (w < 3) ? OFF_D0HH : OFF_D1HH;
        int ktx = (w < 3) ? 3 : 8;
#pragma unroll
        for (int kt = 0; kt < 8; ++kt) {
            if (kt < ktx) Bx[kt] = *(const f16x8*)(Wsw + offi + (size_t)(kt * 48 + gt) * 512 + l * 8);
            Bh[kt] = *(const f16x8*)(Wsw + offh + (size_t)(kt * 48 + gt) * 512 + l * 8);
        }
        const float* bb = (w == 0) ? bias4 + 2048 : bias4 + 3072;
        int hc = cg * 16 + (l & 15);
        if (w == 0 || w == 3) { bR = bb[hc]; bZ = bb[256 + hc]; bNi = bb[512 + hc]; bNh = bb[768 + hc]; }
    }
    // fc weights -> registers (used by cg==0 only; loaded by all to stay uniform)
    f16x8 Bf1a[8], Bf1b[8], Bf2[4];
#pragma unroll
    for (int kt = 0; kt < 8; ++kt) {
        Bf1a[kt] = *(const f16x8*)(Wsw + OFF_FC1 + (size_t)(kt * 8 + w) * 512 + l * 8);
        Bf1b[kt] = (w < 2) ? *(const f16x8*)(Wsw + OFF_FC1 + (size_t)(kt * 8 + w + 6) * 512 + l * 8)
                           : Bf1a[kt];
    }
#pragma unroll
    for (int kt = 0; kt < 4; ++kt)
        Bf2[kt] = *(const f16x8*)(Wsw + OFF_FC2 + (size_t)kt * 512 + l * 8);
    float f1b0 = fc1b[w * 16 + (l & 15)];
    float f1b1 = (w < 2) ? fc1b[(w + 6) * 16 + (l & 15)] : 0.f;
    float f2breg = fc2b[l & 15];

    const float* xsrc1 = x_tgt + (size_t)(g16 + (tid >> 4)) * (256 * 64) + (tid & 15) * 4;
    if (tid < 256) xpre = *(const float4*)xsrc1;
    __syncthreads();

    // ================= decoder: s = 0..255, 2 barriers + 1 pv-wait per step ====
    for (int s = 0; s < 256; ++s) {
        if (tid < 256) {
            int row = tid >> 4, c4 = (tid & 15) * 4;
            XF[row * XSTR + c4]     = (_Float16)xpre.x;
            XF[row * XSTR + c4 + 1] = (_Float16)xpre.y;
            XF[row * XSTR + c4 + 2] = (_Float16)xpre.z;
            XF[row * XSTR + c4 + 3] = (_Float16)xpre.w;
        }
        if (s > 0 && w == 0 && l == 0)
            while (__hip_atomic_load(pvflag, __ATOMIC_RELAXED, __HIP_MEMORY_SCOPE_AGENT) < s)
                __builtin_amdgcn_s_sleep(1);
        __syncthreads();
        if (tid < 256) {
            int row = tid >> 4, col = tid & 15;
            if (s == 0) {
                XF[row * XSTR + 64 + col] = (_Float16)pv_init[(g16 + row) * 16 + col];
            } else {
                union { unsigned short u; _Float16 h; } cv;
                cv.u = load_coh_u16(pvex + (size_t)(g16 + row) * 16 + col);
                XF[row * XSTR + 64 + col] = cv.h;
            }
        }
        stage_h(h0ex + (size_t)((s - 1) & 1) * 65536 + (size_t)g16 * 256, HA0, tid);
        __syncthreads();
        if (tid < 256 && s + 1 < 256) xpre = *(const float4*)(xsrc1 + (size_t)(s + 1) * 64);

        // ---- stage A: d0 ----
        if (w < 3) {
            f32x4 accX = mmk<3>(XFp, Bx);
            f32x4 accH = mmk<8>(HA0p, Bh);
            float* Gb = &G[0][0][0];
#pragma unroll
            for (int i = 0; i < 4; ++i) {
                int rc = ((l >> 4) * 4 + i) * 17 + (l & 15);
                if (j < 2) Gb[j * 272 + rc] = accX[i] + accH[i];
                else { Gb[2 * 272 + rc] = accX[i]; Gb[3 * 272 + rc] = accH[i]; }
            }
        }
        __syncthreads();
        if (w == 0)
            h_update(&G[0][0][0], H0M, h0ex + (size_t)(s & 1) * 65536 + slice_off, l, bR, bZ, bNi, bNh);
        barrier(++ticket);

        // ---- stage B: d1 ----
        stage_h2(h0ex + (size_t)(s & 1) * 65536 + (size_t)g16 * 256,
                 h1ex + (size_t)((s - 1) & 1) * 65536 + (size_t)g16 * 256, HA0, HA1, tid);
        __syncthreads();
        if (w >= 3) {
            f32x4 accX = mmk<8>(HA0p, Bx);
            f32x4 accH = mmk<8>(HA1p, Bh);
            float* Gb = &G[1][0][0];
#pragma unroll
            for (int i = 0; i < 4; ++i) {
                int rc = ((l >> 4) * 4 + i) * 17 + (l & 15);
                if (j < 2) Gb[j * 272 + rc] = accX[i] + accH[i];
                else { Gb[2 * 272 + rc] = accX[i]; Gb[3 * 272 + rc] = accH[i]; }
            }
        }
        __syncthreads();
        if (w == 3)
            h_update(&G[1][0][0], H1M, h1ex + (size_t)(s & 1) * 65536 + slice_off, l, bR, bZ, bNi, bNh);
        barrier(++ticket);

        // ---- fc head: block cg==0 only ----
        if (cg == 0) {
            stage_h(h1ex + (size_t)(s & 1) * 65536 + (size_t)g16 * 256, HA1, tid);
            __syncthreads();
            {
                f32x4 a0 = {0.f,0.f,0.f,0.f}, a1 = a0;
                const _Float16* Ap = HA1 + (l & 15) * HSTR + ((l >> 4) * 8);
#pragma unroll
                for (int kt = 0; kt < 8; ++kt) {
                    f16x8 a = *(const f16x8*)(Ap + kt * 32);
                    a0 = mfma(a, Bf1a[kt], a0);
                    a1 = mfma(a, Bf1b[kt], a1);
                }
#pragma unroll
                for (int i = 0; i < 4; ++i) {
                    int row = (l >> 4) * 4 + i, col = l & 15;
                    YF[row * YSTR + w * 16 + col] = (_Float16)fmaxf(a0[i] + f1b0, 0.f);
                    if (w < 2)
                        YF[row * YSTR + (w + 6) * 16 + col] = (_Float16)fmaxf(a1[i] + f1b1, 0.f);
                }
            }
            __syncthreads();
            if (w == 0) {
                f32x4 acc = {0.f,0.f,0.f,0.f};
                const _Float16* Yp = YF + (l & 15) * YSTR + ((l >> 4) * 8);
#pragma unroll
                for (int kt = 0; kt < 4; ++kt)
                    acc = mfma(*(const f16x8*)(Yp + kt * 32), Bf2[kt], acc);
#pragma unroll
                for (int i = 0; i < 4; ++i) {
                    int row = (l >> 4) * 4 + i, col = l & 15;
                    float y = acc[i] + f2breg;
                    out[(size_t)(g16 + row) * 4096 + (size_t)s * 16 + col] = y;
                    store_coh_f16(pvex + (size_t)(g16 + row) * 16 + col, (_Float16)y);
                }
                asm volatile("s_waitcnt vmcnt(0)" ::: "memory");
                if (l == 0)
                    __hip_atomic_store(pvflag, s + 1, __ATOMIC_RELAXED, __HIP_MEMORY_SCOPE_AGENT);
            }
        }
    }
}

extern "C" void kernel_launch(void* const* d_in, const int* in_sizes, int n_in,
                              void* d_out, int out_size, void* d_ws, size_t ws_size,
                              hipStream_t stream)
{
    const float* x_cv    = (const float*)d_in[0];
    const float* x_tgt   = (const float*)d_in[1];
    const float* pv_init = (const float*)d_in[2];
    const int*   scen    = (const int*)d_in[3];
    const float* emb     = (const float*)d_in[4];
    const float* eWih0 = (const float*)d_in[5];
    const float* eWhh0 = (const float*)d_in[6];
    const float* ebih0 = (const float*)d_in[7];
    const float* ebhh0 = (const float*)d_in[8];
    const float* eWih1 = (const float*)d_in[9];
    const float* eWhh1 = (const float*)d_in[10];
    const float* ebih1 = (const float*)d_in[11];
    const float* ebhh1 = (const float*)d_in[12];
    const float* dWih0 = (const float*)d_in[13];
    const float* dWhh0 = (const float*)d_in[14];
    const float* dbih0 = (const float*)d_in[15];
    const float* dbhh0 = (const float*)d_in[16];
    const float* dWih1 = (const float*)d_in[17];
    const float* dWhh1 = (const float*)d_in[18];
    const float* dbih1 = (const float*)d_in[19];
    const float* dbhh1 = (const float*)d_in[20];
    const float* fc1W = (const float*)d_in[21];
    const float* fc1b = (const float*)d_in[22];
    const float* fc2W = (const float*)d_in[23];
    const float* fc2b = (const float*)d_in[24];
    float* out = (float*)d_out;

    _Float16* W = (_Float16*)d_ws;
    float* bias = (float*)((char*)d_ws + BIAS_BYTE_OFF);
    char* exch = (char*)d_ws + EXCH_BYTE_OFF;

    // zero flags + exchange (h0ex/h1ex zero-init doubles as h(-1)=0)
    hipMemsetAsync(exch, 0, EX_BYTES, stream);

    auto lp = [&](const float* src, unsigned off, int K_src, int KT, int GT) {
        int total = KT * GT * 64;
        prep_w<<<(total + 255) / 256, 256, 0, stream>>>(src, W + off, K_src, GT, total);
    };
    lp(eWih0, OFF_E0IH, 96, 3, 48);
    lp(eWhh0, OFF_E0HH, 256, 8, 48);
    lp(eWih1, OFF_E1IH, 256, 8, 48);
    lp(eWhh1, OFF_E1HH, 256, 8, 48);
    lp(dWih0, OFF_D0IH, 80, 3, 48);    // K 80 zero-padded to 96
    lp(dWhh0, OFF_D0HH, 256, 8, 48);
    lp(dWih1, OFF_D1IH, 256, 8, 48);
    lp(dWhh1, OFF_D1HH, 256, 8, 48);
    lp(fc1W, OFF_FC1, 256, 8, 8);
    lp(fc2W, OFF_FC2, 128, 4, 1);
    prep_bias<<<1, 256, 0, stream>>>(ebih0, ebhh0, bias);
    prep_bias<<<1, 256, 0, stream>>>(ebih1, ebhh1, bias + 1024);
    prep_bias<<<1, 256, 0, stream>>>(dbih0, dbhh0, bias + 2048);
    prep_bias<<<1, 256, 0, stream>>>(dbih1, dbhh1, bias + 3072);

    plant<<<256, 384, 0, stream>>>(x_cv, x_tgt, pv_init, scen, emb,
                                   W, bias, fc1b, fc2b, exch, out);
}

// Round 6
// 3498.389 us; speedup vs baseline: 1.5242x; 1.5242x over previous
//
#include <hip/hip_runtime.h>

// GRUPlant tensor-parallel persistent kernel, round 11.
// Back to the r5-proven IC-scope (sc0 sc1) exchange everywhere; the sc0-only
// L2 fast path is abandoned (4 opaque failures, likely poll-on-stale-L1 hangs).
// Structural change vs r5: barrier+stage FUSION. The inter-block barrier's
// polling threads (tid<256; lane's producer c = tid&15) poll flag[c] and
// immediately load producer c's 32B h-slice inside the barrier, overlapping
// data RT with flag skew and removing two sync hops per round. Redundant
// staging removed: decoder barrier-B stages nothing (HA0 already holds h0(s)
// from barrier-A) except on cg0 (h1 for the fc head); encoder t=512 flush
// round needs no barrier (decoder barrier-A(0) subsumes it).

typedef _Float16 f16x8 __attribute__((ext_vector_type(8)));
typedef float f32x4 __attribute__((ext_vector_type(4)));

#define XSTR 104   // 96 + 8 pad (f16)
#define HSTR 264   // 256 + 8 pad (f16)
#define YSTR 136   // 128 + 8 pad (f16)

// ---- pre-swizzled weight layout in d_ws (f16 elems; chunk = 512 f16 = 1KB) ----
#define OFF_E0IH 0u
#define OFF_E0HH 73728u
#define OFF_E1IH 270336u
#define OFF_E1HH 466944u
#define OFF_D0IH 663552u     // K=80 zero-padded to 96
#define OFF_D0HH 737280u
#define OFF_D1IH 933888u
#define OFF_D1HH 1130496u
#define OFF_FC1  1327104u    // 8kt x 8gt
#define OFF_FC2  1359872u    // 4kt x 1gt
#define W_TOTAL_F16 1361920u
#define BIAS_BYTE_OFF 2723840u
#define EXCH_BYTE_OFF 2740224u
// ---- exchange region (bytes, relative) ---- (EXACT round-5 footprint)
#define EX_H0 0          // [2][256][256] f16
#define EX_H1 262144     // [2][256][256] f16
#define EX_PV 524288     // [256][16] f16
#define EX_FLAGS 532480  // 16 groups x 17 flags x 128 B
#define EX_BYTES 567296

__device__ __forceinline__ float sigm(float x) { return 1.f / (1.f + __expf(-x)); }
__device__ __forceinline__ float tanh_fast(float x) { return 1.f - 2.f / (__expf(2.f * x) + 1.f); }

__device__ __forceinline__ f32x4 mfma(f16x8 a, f16x8 b, f32x4 c) {
    return __builtin_amdgcn_mfma_f32_16x16x32_f16(a, b, c, 0, 0, 0);
}

// ---- coherent (IC-level) memory helpers: bypass L1+L2 via sc0 sc1 ----
__device__ __forceinline__ void store_coh_f16(_Float16* p, _Float16 v) {
    union { _Float16 h; unsigned short u; } cv; cv.h = v;
    unsigned int ui = cv.u;
    asm volatile("global_store_short %0, %1, off sc0 sc1" :: "v"(p), "v"(ui) : "memory");
}
__device__ __forceinline__ unsigned short load_coh_u16(const _Float16* p) {
    unsigned int r;
    asm volatile("global_load_ushort %0, %1, off sc0 sc1\n\ts_waitcnt vmcnt(0)"
                 : "=v"(r) : "v"(p) : "memory");
    return (unsigned short)r;
}
__device__ __forceinline__ void store_flag(int* p, int v) {
    asm volatile("global_store_dword %0, %1, off sc0 sc1" :: "v"(p), "v"(v) : "memory");
}
__device__ __forceinline__ int load_flag(const int* p) {
    int r;
    asm volatile("global_load_dword %0, %1, off sc0 sc1\n\ts_waitcnt vmcnt(0)"
                 : "=v"(r) : "v"(p) : "memory");
    return r;
}

// ---- prep: swizzle (rows x K_src) fp32 weight into MFMA-B fragment chunks ----
__global__ __launch_bounds__(256) void prep_w(const float* __restrict__ W,
                                              _Float16* __restrict__ dst,
                                              int K_src, int GT, int total_threads) {
    int idx = blockIdx.x * 256 + threadIdx.x;
    if (idx >= total_threads) return;
    int l = idx & 63, c = idx >> 6;
    int kt = c / GT, gt = c - kt * GT;
    int g = gt * 16 + (l & 15);
    int k0 = kt * 32 + (l >> 4) * 8;
    _Float16 tmp[8];
#pragma unroll
    for (int j = 0; j < 8; ++j) {
        int k = k0 + j;
        tmp[j] = (k < K_src) ? (_Float16)W[(size_t)g * K_src + k] : (_Float16)0.f;
    }
    *(f16x8*)(dst + (size_t)c * 512 + (size_t)l * 8) = *(f16x8*)tmp;
}

__global__ __launch_bounds__(256) void prep_bias(const float* __restrict__ bih,
                                                 const float* __restrict__ bhh,
                                                 float* __restrict__ dst) {
    int i = threadIdx.x;
    dst[i]       = bih[i]       + bhh[i];
    dst[256 + i] = bih[256 + i] + bhh[256 + i];
    dst[512 + i] = bih[512 + i];
    dst[768 + i] = bhh[512 + i];
}

template <int KT>
__device__ __forceinline__ f32x4 mmk(const _Float16* ap, const f16x8 (&B)[8]) {
    f32x4 acc = {0.f, 0.f, 0.f, 0.f};
#pragma unroll
    for (int kt = 0; kt < KT; ++kt)
        acc = mfma(*(const f16x8*)(ap + kt * 32), B[kt], acc);
    return acc;
}

__device__ __forceinline__ void h_update(const float* Gb, float* HM,
                                         _Float16* hex_slice, int l,
                                         float bR, float bZ, float bNi, float bNh) {
#pragma unroll
    for (int i = 0; i < 4; ++i) {
        int row = (l >> 4) * 4 + i, col = l & 15;
        int rc = row * 17 + col;
        float r = sigm(Gb[rc] + bR);
        float z = sigm(Gb[272 + rc] + bZ);
        float n = tanh_fast(Gb[2 * 272 + rc] + bNi + r * (Gb[3 * 272 + rc] + bNh));
        float hp = HM[row * 16 + col];
        float hn = (1.f - z) * n + z * hp;
        HM[row * 16 + col] = hn;
        store_coh_f16(hex_slice + (size_t)row * 256 + col, (_Float16)hn);
    }
}

__global__ __launch_bounds__(384, 2) void plant(
    const float* __restrict__ x_cv, const float* __restrict__ x_tgt,
    const float* __restrict__ pv_init, const int* __restrict__ scen,
    const float* __restrict__ emb,
    const _Float16* __restrict__ Wsw, const float* __restrict__ bias4,
    const float* __restrict__ fc1b, const float* __restrict__ fc2b,
    char* __restrict__ exch, float* __restrict__ out)
{
    __shared__ _Float16 XF[16 * XSTR];
    __shared__ _Float16 HA0[16 * HSTR];
    __shared__ _Float16 HA1[16 * HSTR];
    __shared__ _Float16 YF[16 * YSTR];
    __shared__ float G[2][4][272];
    __shared__ float H0M[256], H1M[256];

    const int tid = threadIdx.x;
    const int l = tid & 63, w = tid >> 6;
    const int g = blockIdx.x >> 4, cg = blockIdx.x & 15;
    const int g16 = g * 16;
    const int j = (w < 3) ? w : w - 3;      // gate role: 0=r,1=z,2=n
    const int gt = j * 16 + cg;

    _Float16* h0ex = (_Float16*)(exch + EX_H0);
    _Float16* h1ex = (_Float16*)(exch + EX_H1);
    _Float16* pvex = (_Float16*)(exch + EX_PV);
    int* gflags = (int*)(exch + EX_FLAGS) + g * (17 * 32);
    int* pvflag = gflags + 16 * 32;

    const int arow = l & 15, acol8 = (l >> 4) * 8;
    const size_t slice_off = (size_t)g16 * 256 + cg * 16;
    const _Float16* XFp = XF + arow * XSTR + acol8;
    const _Float16* HA0p = HA0 + arow * HSTR + acol8;
    const _Float16* HA1p = HA1 + arow * HSTR + acol8;

    int ticket = 0;

    // plain flag barrier (no staging)
    auto barrier0 = [&](int target) {
        __syncthreads();   // drains vmcnt per wave -> all coherent stores done
        if (w == 0) {
            if (l == 0) store_flag(&gflags[cg * 32], target);
            if (l < 16)
                while (load_flag(&gflags[l * 32]) < target)
                    __builtin_amdgcn_s_sleep(1);
        }
        __syncthreads();
    };
    // fused barrier + one-matrix stage: poll producer c, then load its slice
    auto barrier_stage1 = [&](int target, const _Float16* s0, _Float16* d0) {
        __syncthreads();
        if (tid == 0) store_flag(&gflags[cg * 32], target);
        if (tid < 256) {
            int c = tid & 15, row = tid >> 4;
            while (load_flag(&gflags[c * 32]) < target) __builtin_amdgcn_s_sleep(1);
            const _Float16* p0 = s0 + (size_t)row * 256 + c * 16;
            f16x8 a, b;
            asm volatile(
                "global_load_dwordx4 %0, %2, off sc0 sc1\n\t"
                "global_load_dwordx4 %1, %2, off offset:16 sc0 sc1\n\t"
                "s_waitcnt vmcnt(0)"
                : "=v"(a), "=v"(b) : "v"(p0) : "memory");
            *(f16x8*)(d0 + row * HSTR + c * 16) = a;
            *(f16x8*)(d0 + row * HSTR + c * 16 + 8) = b;
        }
        __syncthreads();
    };
    // fused barrier + two-matrix stage
    auto barrier_stage2 = [&](int target, const _Float16* s0, _Float16* d0,
                              const _Float16* s1, _Float16* d1) {
        __syncthreads();
        if (tid == 0) store_flag(&gflags[cg * 32], target);
        if (tid < 256) {
            int c = tid & 15, row = tid >> 4;
            while (load_flag(&gflags[c * 32]) < target) __builtin_amdgcn_s_sleep(1);
            const _Float16* p0 = s0 + (size_t)row * 256 + c * 16;
            const _Float16* p1 = s1 + (size_t)row * 256 + c * 16;
            f16x8 a, b, e, f;
            asm volatile(
                "global_load_dwordx4 %0, %4, off sc0 sc1\n\t"
                "global_load_dwordx4 %1, %4, off offset:16 sc0 sc1\n\t"
                "global_load_dwordx4 %2, %5, off sc0 sc1\n\t"
                "global_load_dwordx4 %3, %5, off offset:16 sc0 sc1\n\t"
                "s_waitcnt vmcnt(0)"
                : "=v"(a), "=v"(b), "=v"(e), "=v"(f) : "v"(p0), "v"(p1) : "memory");
            *(f16x8*)(d0 + row * HSTR + c * 16) = a;
            *(f16x8*)(d0 + row * HSTR + c * 16 + 8) = b;
            *(f16x8*)(d1 + row * HSTR + c * 16) = e;
            *(f16x8*)(d1 + row * HSTR + c * 16 + 8) = f;
        }
        __syncthreads();
    };

    // ---- init ----
    for (int i = tid; i < 256; i += 384) { H0M[i] = 0.f; H1M[i] = 0.f; }
    if (tid < 256) {                        // scenario embedding -> XF[64..95]
        int row = tid >> 4, c2 = (tid & 15) * 2;
        int sc = scen[g16 + row];
        XF[row * XSTR + 64 + c2]     = (_Float16)emb[sc * 32 + c2];
        XF[row * XSTR + 64 + c2 + 1] = (_Float16)emb[sc * 32 + c2 + 1];
    }
    if (tid < 256) {                        // HA0 = h0(-1) = 0
        int row = tid >> 4, c = tid & 15;
        f16x8 z = {};
        *(f16x8*)(HA0 + row * HSTR + c * 16) = z;
        *(f16x8*)(HA0 + row * HSTR + c * 16 + 8) = z;
    }

    // encoder gate weights -> registers
    f16x8 Bx[8], Bh[8];
    {
        unsigned offi = (w < 3) ? OFF_E0IH : OFF_E1IH;
        unsigned offh = (w < 3) ? OFF_E0HH : OFF_E1HH;
        int ktx = (w < 3) ? 3 : 8;
#pragma unroll
        for (int kt = 0; kt < 8; ++kt) {
            if (kt < ktx) Bx[kt] = *(const f16x8*)(Wsw + offi + (size_t)(kt * 48 + gt) * 512 + l * 8);
            Bh[kt] = *(const f16x8*)(Wsw + offh + (size_t)(kt * 48 + gt) * 512 + l * 8);
        }
    }
    float bR = 0.f, bZ = 0.f, bNi = 0.f, bNh = 0.f;
    {
        const float* bb = (w == 0) ? bias4 : bias4 + 1024;
        int hc = cg * 16 + (l & 15);
        if (w == 0 || w == 3) { bR = bb[hc]; bZ = bb[256 + hc]; bNi = bb[512 + hc]; bNh = bb[768 + hc]; }
    }

    float4 xpre;
    const float* xsrc0 = x_cv + (size_t)(g16 + (tid >> 4)) * (512 * 64) + (tid & 15) * 4;
    if (tid < 256) {                        // XF(0) direct; xpre = x(1)
        float4 x0 = *(const float4*)xsrc0;
        int row = tid >> 4, c4 = (tid & 15) * 4;
        XF[row * XSTR + c4]     = (_Float16)x0.x;
        XF[row * XSTR + c4 + 1] = (_Float16)x0.y;
        XF[row * XSTR + c4 + 2] = (_Float16)x0.z;
        XF[row * XSTR + c4 + 3] = (_Float16)x0.w;
        xpre = *(const float4*)(xsrc0 + 64);
    }
    __syncthreads();

    // ========== encoder: t = 0..511 (layer1 lags by 1; flush in epilogue) =====
    for (int t = 0; t < 512; ++t) {
        // entry: HA0 = h0(t-1), HA1 = h1(t-2), XF = x(t)+emb
        bool doL1 = (w >= 3) && (t > 0);
        if (w < 3 || doL1) {
            f32x4 accX, accH;
            if (w < 3) { accX = mmk<3>(XFp, Bx);  accH = mmk<8>(HA0p, Bh); }
            else       { accX = mmk<8>(HA0p, Bx); accH = mmk<8>(HA1p, Bh); }
            float* Gb = &G[(w < 3) ? 0 : 1][0][0];
#pragma unroll
            for (int i = 0; i < 4; ++i) {
                int rc = ((l >> 4) * 4 + i) * 17 + (l & 15);
                if (j < 2) Gb[j * 272 + rc] = accX[i] + accH[i];
                else { Gb[2 * 272 + rc] = accX[i]; Gb[3 * 272 + rc] = accH[i]; }
            }
        }
        __syncthreads();
        if (w == 0)
            h_update(&G[0][0][0], H0M, h0ex + (size_t)(t & 1) * 65536 + slice_off, l, bR, bZ, bNi, bNh);
        if (w == 3 && t > 0)
            h_update(&G[1][0][0], H1M, h1ex + (size_t)((t - 1) & 1) * 65536 + slice_off, l, bR, bZ, bNi, bNh);
        if (tid < 256 && t + 1 < 512) {     // XF(t+1); layer0 already consumed XF(t)
            int row = tid >> 4, c4 = (tid & 15) * 4;
            XF[row * XSTR + c4]     = (_Float16)xpre.x;
            XF[row * XSTR + c4 + 1] = (_Float16)xpre.y;
            XF[row * XSTR + c4 + 2] = (_Float16)xpre.z;
            XF[row * XSTR + c4 + 3] = (_Float16)xpre.w;
        }
        if (tid < 256 && t + 2 < 512) xpre = *(const float4*)(xsrc0 + (size_t)(t + 2) * 64);
        // fused barrier: HA0 <- h0(t), HA1 <- h1(t-1)
        barrier_stage2(++ticket,
                       h0ex + (size_t)(t & 1) * 65536 + (size_t)g16 * 256, HA0,
                       h1ex + (size_t)((t & 1) ^ 1) * 65536 + (size_t)g16 * 256, HA1);
    }
    // ---- encoder epilogue (t = 512): layer1 computes h1(511); no barrier here:
    // decoder barrier-A(0)'s opening sync + flag ordering covers visibility.
    if (w >= 3) {
        f32x4 accX = mmk<8>(HA0p, Bx);      // HA0 = h0(511)
        f32x4 accH = mmk<8>(HA1p, Bh);      // HA1 = h1(510)
        float* Gb = &G[1][0][0];
#pragma unroll
        for (int i = 0; i < 4; ++i) {
            int rc = ((l >> 4) * 4 + i) * 17 + (l & 15);
            if (j < 2) Gb[j * 272 + rc] = accX[i] + accH[i];
            else { Gb[2 * 272 + rc] = accX[i]; Gb[3 * 272 + rc] = accH[i]; }
        }
    }
    __syncthreads();
    if (w == 3)
        h_update(&G[1][0][0], H1M, h1ex + (size_t)1 * 65536 + slice_off, l, bR, bZ, bNi, bNh);

    // ================= phase switch: decoder weights =================
    {
        unsigned offi = (w < 3) ? OFF_D0IH : OFF_D1IH;
        unsigned offh = (w < 3) ? OFF_D0HH : OFF_D1HH;
        int ktx = (w < 3) ? 3 : 8;
#pragma unroll
        for (int kt = 0; kt < 8; ++kt) {
            if (kt < ktx) Bx[kt] = *(const f16x8*)(Wsw + offi + (size_t)(kt * 48 + gt) * 512 + l * 8);
            Bh[kt] = *(const f16x8*)(Wsw + offh + (size_t)(kt * 48 + gt) * 512 + l * 8);
        }
        const float* bb = (w == 0) ? bias4 + 2048 : bias4 + 3072;
        int hc = cg * 16 + (l & 15);
        if (w == 0 || w == 3) { bR = bb[hc]; bZ = bb[256 + hc]; bNi = bb[512 + hc]; bNh = bb[768 + hc]; }
    }
    // fc weights -> registers (used by cg==0 only; loaded by all to stay uniform)
    f16x8 Bf1a[8], Bf1b[8], Bf2[4];
#pragma unroll
    for (int kt = 0; kt < 8; ++kt) {
        Bf1a[kt] = *(const f16x8*)(Wsw + OFF_FC1 + (size_t)(kt * 8 + w) * 512 + l * 8);
        Bf1b[kt] = (w < 2) ? *(const f16x8*)(Wsw + OFF_FC1 + (size_t)(kt * 8 + w + 6) * 512 + l * 8)
                           : Bf1a[kt];
    }
#pragma unroll
    for (int kt = 0; kt < 4; ++kt)
        Bf2[kt] = *(const f16x8*)(Wsw + OFF_FC2 + (size_t)kt * 512 + l * 8);
    float f1b0 = fc1b[w * 16 + (l & 15)];
    float f1b1 = (w < 2) ? fc1b[(w + 6) * 16 + (l & 15)] : 0.f;
    float f2breg = fc2b[l & 15];

    const float* xsrc1 = x_tgt + (size_t)(g16 + (tid >> 4)) * (256 * 64) + (tid & 15) * 4;
    if (tid < 256) xpre = *(const float4*)xsrc1;
    __syncthreads();

    // ================= decoder: s = 0..255 ====================================
    for (int s = 0; s < 256; ++s) {
        // entry: HA0 = h0(s-1) (s=0: h0(511) from encoder barrier(511))
        if (tid < 256) {
            int row = tid >> 4, c4 = (tid & 15) * 4;
            XF[row * XSTR + c4]     = (_Float16)xpre.x;
            XF[row * XSTR + c4 + 1] = (_Float16)xpre.y;
            XF[row * XSTR + c4 + 2] = (_Float16)xpre.z;
            XF[row * XSTR + c4 + 3] = (_Float16)xpre.w;
        }
        if (s > 0 && w == 0 && l == 0)
            while (load_flag(pvflag) < s)
                __builtin_amdgcn_s_sleep(1);
        __syncthreads();
        if (tid < 256) {
            int row = tid >> 4, col = tid & 15;
            if (s == 0) {
                XF[row * XSTR + 64 + col] = (_Float16)pv_init[(g16 + row) * 16 + col];
            } else {
                union { unsigned short u; _Float16 h; } cv;
                cv.u = load_coh_u16(pvex + (size_t)(g16 + row) * 16 + col);
                XF[row * XSTR + 64 + col] = cv.h;
            }
        }
        __syncthreads();
        if (tid < 256 && s + 1 < 256) xpre = *(const float4*)(xsrc1 + (size_t)(s + 1) * 64);

        // ---- stage A: d0 ----
        if (w < 3) {
            f32x4 accX = mmk<3>(XFp, Bx);
            f32x4 accH = mmk<8>(HA0p, Bh);
            float* Gb = &G[0][0][0];
#pragma unroll
            for (int i = 0; i < 4; ++i) {
                int rc = ((l >> 4) * 4 + i) * 17 + (l & 15);
                if (j < 2) Gb[j * 272 + rc] = accX[i] + accH[i];
                else { Gb[2 * 272 + rc] = accX[i]; Gb[3 * 272 + rc] = accH[i]; }
            }
        }
        __syncthreads();
        if (w == 0)
            h_update(&G[0][0][0], H0M, h0ex + (size_t)(s & 1) * 65536 + slice_off, l, bR, bZ, bNi, bNh);
        // fused barrier A: HA0 <- h0(s); HA1 <- h1(s-1)
        barrier_stage2(++ticket,
                       h0ex + (size_t)(s & 1) * 65536 + (size_t)g16 * 256, HA0,
                       h1ex + (size_t)((s & 1) ^ 1) * 65536 + (size_t)g16 * 256, HA1);

        // ---- stage B: d1 ----
        if (w >= 3) {
            f32x4 accX = mmk<8>(HA0p, Bx);   // x-input = h0(s)
            f32x4 accH = mmk<8>(HA1p, Bh);   // h = h1(s-1)
            float* Gb = &G[1][0][0];
#pragma unroll
            for (int i = 0; i < 4; ++i) {
                int rc = ((l >> 4) * 4 + i) * 17 + (l & 15);
                if (j < 2) Gb[j * 272 + rc] = accX[i] + accH[i];
                else { Gb[2 * 272 + rc] = accX[i]; Gb[3 * 272 + rc] = accH[i]; }
            }
        }
        __syncthreads();
        if (w == 3)
            h_update(&G[1][0][0], H1M, h1ex + (size_t)(s & 1) * 65536 + slice_off, l, bR, bZ, bNi, bNh);
        // barrier B: HA0 still holds h0(s) for phase A(s+1) (no re-stage).
        // cg0 stages h1(s) for the fc head; others: pure flag barrier.
        if (cg == 0)
            barrier_stage1(++ticket, h1ex + (size_t)(s & 1) * 65536 + (size_t)g16 * 256, HA1);
        else
            barrier0(++ticket);

        // ---- fc head: block cg==0 only (HA1 = h1(s)) ----
        if (cg == 0) {
            {
                f32x4 a0 = {0.f,0.f,0.f,0.f}, a1 = a0;
                const _Float16* Ap = HA1 + (l & 15) * HSTR + ((l >> 4) * 8);
#pragma unroll
                for (int kt = 0; kt < 8; ++kt) {
                    f16x8 a = *(const f16x8*)(Ap + kt * 32);
                    a0 = mfma(a, Bf1a[kt], a0);
                    a1 = mfma(a, Bf1b[kt], a1);
                }
#pragma unroll
                for (int i = 0; i < 4; ++i) {
                    int row = (l >> 4) * 4 + i, col = l & 15;
                    YF[row * YSTR + w * 16 + col] = (_Float16)fmaxf(a0[i] + f1b0, 0.f);
                    if (w < 2)
                        YF[row * YSTR + (w + 6) * 16 + col] = (_Float16)fmaxf(a1[i] + f1b1, 0.f);
                }
            }
            __syncthreads();
            if (w == 0) {
                f32x4 acc = {0.f,0.f,0.f,0.f};
                const _Float16* Yp = YF + (l & 15) * YSTR + ((l >> 4) * 8);
#pragma unroll
                for (int kt = 0; kt < 4; ++kt)
                    acc = mfma(*(const f16x8*)(Yp + kt * 32), Bf2[kt], acc);
#pragma unroll
                for (int i = 0; i < 4; ++i) {
                    int row = (l >> 4) * 4 + i, col = l & 15;
                    float y = acc[i] + f2breg;
                    out[(size_t)(g16 + row) * 4096 + (size_t)s * 16 + col] = y;
                    store_coh_f16(pvex + (size_t)(g16 + row) * 16 + col, (_Float16)y);
                }
                asm volatile("s_waitcnt vmcnt(0)" ::: "memory");
                if (l == 0)
                    store_flag(pvflag, s + 1);
            }
        }
    }
}

extern "C" void kernel_launch(void* const* d_in, const int* in_sizes, int n_in,
                              void* d_out, int out_size, void* d_ws, size_t ws_size,
                              hipStream_t stream)
{
    const float* x_cv    = (const float*)d_in[0];
    const float* x_tgt   = (const float*)d_in[1];
    const float* pv_init = (const float*)d_in[2];
    const int*   scen    = (const int*)d_in[3];
    const float* emb     = (const float*)d_in[4];
    const float* eWih0 = (const float*)d_in[5];
    const float* eWhh0 = (const float*)d_in[6];
    const float* ebih0 = (const float*)d_in[7];
    const float* ebhh0 = (const float*)d_in[8];
    const float* eWih1 = (const float*)d_in[9];
    const float* eWhh1 = (const float*)d_in[10];
    const float* ebih1 = (const float*)d_in[11];
    const float* ebhh1 = (const float*)d_in[12];
    const float* dWih0 = (const float*)d_in[13];
    const float* dWhh0 = (const float*)d_in[14];
    const float* dbih0 = (const float*)d_in[15];
    const float* dbhh0 = (const float*)d_in[16];
    const float* dWih1 = (const float*)d_in[17];
    const float* dWhh1 = (const float*)d_in[18];
    const float* dbih1 = (const float*)d_in[19];
    const float* dbhh1 = (const float*)d_in[20];
    const float* fc1W = (const float*)d_in[21];
    const float* fc1b = (const float*)d_in[22];
    const float* fc2W = (const float*)d_in[23];
    const float* fc2b = (const float*)d_in[24];
    float* out = (float*)d_out;

    _Float16* W = (_Float16*)d_ws;
    float* bias = (float*)((char*)d_ws + BIAS_BYTE_OFF);
    char* exch = (char*)d_ws + EXCH_BYTE_OFF;

    // zero flags + exchange (h0ex/h1ex zero-init doubles as h(-1)=0)
    hipMemsetAsync(exch, 0, EX_BYTES, stream);

    auto lp = [&](const float* src, unsigned off, int K_src, int KT, int GT) {
        int total = KT * GT * 64;
        prep_w<<<(total + 255) / 256, 256, 0, stream>>>(src, W + off, K_src, GT, total);
    };
    lp(eWih0, OFF_E0IH, 96, 3, 48);
    lp(eWhh0, OFF_E0HH, 256, 8, 48);
    lp(eWih1, OFF_E1IH, 256, 8, 48);
    lp(eWhh1, OFF_E1HH, 256, 8, 48);
    lp(dWih0, OFF_D0IH, 80, 3, 48);    // K 80 zero-padded to 96
    lp(dWhh0, OFF_D0HH, 256, 8, 48);
    lp(dWih1, OFF_D1IH, 256, 8, 48);
    lp(dWhh1, OFF_D1HH, 256, 8, 48);
    lp(fc1W, OFF_FC1, 256, 8, 8);
    lp(fc2W, OFF_FC2, 128, 4, 1);
    prep_bias<<<1, 256, 0, stream>>>(ebih0, ebhh0, bias);
    prep_bias<<<1, 256, 0, stream>>>(ebih1, ebhh1, bias + 1024);
    prep_bias<<<1, 256, 0, stream>>>(dbih0, dbhh0, bias + 2048);
    prep_bias<<<1, 256, 0, stream>>>(dbih1, dbhh1, bias + 3072);

    plant<<<256, 384, 0, stream>>>(x_cv, x_tgt, pv_init, scen, emb,
                                   W, bias, fc1b, fc2b, exch, out);
}